// Round 3
// baseline (137.061 us; speedup 1.0000x reference)
//
#include <hip/hip_runtime.h>
#include <stdint.h>
#include <math.h>

#define A_N 65536
#define B_N 16
#define T_N 64
#define NB  (A_N / 256)      // k1 blocks per image = 256
#define EPSF 1e-6f

// ---------------------------------------------------------------------------
// Workspace:
//   keys        : B * NB * 64 * u64  = 2 MiB  (per-block best candidate key per target)
//   code        : B * A * u8         = 1 MiB  (best_target_idx | thr<<7)
//   partials    : B * NB * 4 * f32   = 64 KiB
//   corrections : B * 4 * f32        = 256 B
// ---------------------------------------------------------------------------

__device__ __forceinline__ void emit_cand(
    int s, const float4* tb, const float* ta, float a1, float4 an,
    unsigned int lo, unsigned long long* slot)
{
    const float4 tbx = tb[s];
    float x1 = fmaxf(an.x, tbx.x), y1 = fmaxf(an.y, tbx.y);
    float x2 = fminf(an.z, tbx.z), y2 = fminf(an.w, tbx.w);
    float inter = fmaxf(x2 - x1, 0.f) * fmaxf(y2 - y1, 0.f);
    float ue = ((a1 + ta[s]) - inter) + EPSF;          // np-exact association
    float iou = inter / ue;                            // IEEE-exact
    unsigned long long key = ((unsigned long long)__float_as_uint(iou) << 32)
                           | (unsigned long long)lo;
    atomicMax(&slot[s], key);
}

// K1: branch-free IoU sweep + per-anchor argmax/threshold + candidate bitmask
//     (candidates resolved post-loop) + loss terms under pos:=thr.
__global__ __launch_bounds__(256) void k1_main(
    const float4* __restrict__ anchors,
    const float4* __restrict__ bbox,
    const float*  __restrict__ conf,
    const float4* __restrict__ cls,       // 20 floats/anchor = 5 x float4
    const float4* __restrict__ tboxes,
    const int*    __restrict__ tlabels,
    unsigned long long* __restrict__ keys,
    unsigned char* __restrict__ code,
    float* __restrict__ partials)
{
    __shared__ float4 tb[T_N];
    __shared__ float  ta[T_N];
    __shared__ int    tl[T_N];
    __shared__ unsigned long long slot[T_N];
    const int b   = blockIdx.y;
    const int tid = threadIdx.x;
    if (tid < T_N) {
        float4 t = tboxes[b * T_N + tid];
        tb[tid] = t;
        ta[tid] = (t.z - t.x) * (t.w - t.y);
        tl[tid] = tlabels[b * T_N + tid];
        slot[tid] = 0ull;
    }
    __syncthreads();

    const int a = blockIdx.x * 256 + tid;
    const float4 an = anchors[a];
    const float a1 = (an.z - an.x) * (an.w - an.y);
    const unsigned int lo = ~(unsigned int)a;   // smaller idx -> larger lo

    // init: first step always wins (inter*1 >= 0 > -ue), then strict-greater
    // keeps the first max (np argmax semantics).
    float b_inter = -1.f, b_ue = 1.f;
    int   b_t = 0;
    unsigned int mlo = 0u, mhi = 0u;

    #pragma unroll
    for (int s = 0; s < 64; ++s) {
        const float4 tbx = tb[s];
        const float x1 = fmaxf(an.x, tbx.x), y1 = fmaxf(an.y, tbx.y);
        const float x2 = fminf(an.z, tbx.z), y2 = fminf(an.w, tbx.w);
        const float inter = fmaxf(x2 - x1, 0.f) * fmaxf(y2 - y1, 0.f);
        const float ue = ((a1 + ta[s]) - inter) + EPSF;   // np-exact
        const bool upd = (inter * b_ue > b_inter * ue);
        if (upd) { b_inter = inter; b_ue = ue; b_t = s; }
        // candidate: ratio >= ~0.2499 (margin-safe superset of iou>=0.25)
        const unsigned int c = (fmaf(-0.2499f, ue, inter) >= 0.f) ? 1u : 0u;
        if (s < 32) mlo = mlo + mlo + c;   // bit (31-s)
        else        mhi = mhi + mhi + c;   // bit (63-s)
    }

    // resolve candidates (avg ~0.5/anchor): exact division + LDS atomicMax
    unsigned int w0 = mlo;
    while (w0) {
        int p = __builtin_ctz(w0); w0 &= w0 - 1;
        emit_cand(31 - p, tb, ta, a1, an, lo, slot);
    }
    unsigned int w1 = mhi;
    while (w1) {
        int p = __builtin_ctz(w1); w1 &= w1 - 1;
        emit_cand(63 - p, tb, ta, a1, an, lo, slot);
    }

    const bool thr = (b_inter >= 0.5f * b_ue);   // max_iou >= POS_THR (exact)
    const size_t ba = (size_t)b * A_N + a;
    code[ba] = (unsigned char)(b_t | (thr ? 128 : 0));

    // losses with ct := thr
    const float p  = conf[ba];
    const float w  = thr ? (1.f - p) : p;
    const float fw = w * sqrtf(w);                               // w^1.5
    const float bce = thr ? -logf(p + EPSF) : -logf(1.f - p + EPSF);
    const float cterm = bce * fw * 0.5f;                         // alpha == 0.5

    float bterm = 0.f, clterm = 0.f;
    if (thr) {
        const float4 pb = bbox[ba];
        const float4 mb = tb[b_t];
        float x1 = fmaxf(pb.x, mb.x), y1 = fmaxf(pb.y, mb.y);
        float x2 = fminf(pb.z, mb.z), y2 = fminf(pb.w, mb.w);
        float inter = fmaxf(x2 - x1, 0.f) * fmaxf(y2 - y1, 0.f);
        float pa1 = (pb.z - pb.x) * (pb.w - pb.y);
        float pa2 = (mb.z - mb.x) * (mb.w - mb.y);
        float uni = pa1 + pa2 - inter;
        float iou = inter / (uni + EPSF);
        float ex1 = fminf(pb.x, mb.x), ey1 = fminf(pb.y, mb.y);
        float ex2 = fmaxf(pb.z, mb.z), ey2 = fmaxf(pb.w, mb.w);
        float enc = (ex2 - ex1) * (ey2 - ey1);
        float giou = iou - (enc - uni) / (enc + EPSF);
        float gl = 1.f - giou;
        float l1 = 0.25f * (fabsf(pb.x - mb.x) + fabsf(pb.y - mb.y) +
                            fabsf(pb.z - mb.z) + fabsf(pb.w - mb.w));
        bterm = gl + 0.5f * l1;

        const int lab = tl[b_t] - 1;                // 0..19
        const float4* cp = cls + ba * 5;
        float s2 = 0.f, xl = 0.f;
        #pragma unroll
        for (int q = 0; q < 5; ++q) {
            float4 v = cp[q];
            float xs[4] = {v.x, v.y, v.z, v.w};
            #pragma unroll
            for (int j = 0; j < 4; ++j) {
                float x = xs[j];
                s2 += fmaxf(x, 0.f) + log1pf(expf(-fabsf(x)));
                if (q * 4 + j == lab) xl = x;
            }
        }
        clterm = (s2 - xl) * (1.f / 20.f);
    }

    float r0 = cterm, r1 = thr ? 1.f : 0.f, r2 = bterm, r3 = clterm;
    #pragma unroll
    for (int off = 32; off; off >>= 1) {
        r0 += __shfl_down(r0, off, 64);
        r1 += __shfl_down(r1, off, 64);
        r2 += __shfl_down(r2, off, 64);
        r3 += __shfl_down(r3, off, 64);
    }
    __shared__ float red[4][4];
    const int wv = tid >> 6;
    if ((tid & 63) == 0) { red[wv][0] = r0; red[wv][1] = r1; red[wv][2] = r2; red[wv][3] = r3; }
    __syncthreads();   // also guarantees all slot[] atomics are done
    if (tid < 4) {
        float v = red[0][tid] + red[1][tid] + red[2][tid] + red[3][tid];
        partials[(((size_t)b * NB) + blockIdx.x) * 4 + tid] = v;
    }
    if (tid < T_N)
        keys[(((size_t)b * NB + blockIdx.x) << 6) | tid] = slot[tid];
}

// K2: per image — reduce keys to winners, rare exact fallback for empty
//     targets, then forced-only corrections. One block per image.
__global__ __launch_bounds__(1024) void k2_all(
    const unsigned long long* __restrict__ keys,
    const float4* __restrict__ anchors,
    const float4* __restrict__ bbox,
    const float*  __restrict__ conf,
    const float4* __restrict__ cls,
    const float4* __restrict__ tboxes,
    const int*    __restrict__ tlabels,
    const unsigned char* __restrict__ code,
    float* __restrict__ corrections)
{
    __shared__ unsigned long long sh[16][64];
    __shared__ unsigned long long sw[16];
    __shared__ unsigned int winner[64];
    __shared__ int emptyList[64];
    __shared__ int nEmpty;
    const int b = blockIdx.x, tid = threadIdx.x;
    const int t = tid & 63, g = tid >> 6;
    if (tid == 0) nEmpty = 0;

    unsigned long long K = 0ull;
    #pragma unroll 4
    for (int i = 0; i < 16; ++i) {
        unsigned long long k = keys[(((size_t)b * NB + (g * 16 + i)) << 6) | t];
        if (k > K) K = k;
    }
    sh[g][t] = K;
    __syncthreads();
    if (tid < 64) {
        unsigned long long m = sh[0][tid];
        #pragma unroll
        for (int g2 = 1; g2 < 16; ++g2) if (sh[g2][tid] > m) m = sh[g2][tid];
        if (m != 0ull) winner[tid] = ~(unsigned int)(m & 0xFFFFFFFFull);
        else { int i = atomicAdd(&nEmpty, 1); emptyList[i] = tid; }
    }
    __syncthreads();

    const int ne = nEmpty;            // normally 0
    for (int e = 0; e < ne; ++e) {
        const int tt = emptyList[e];
        const float4 tbx = tboxes[b * T_N + tt];
        const float a2 = (tbx.z - tbx.x) * (tbx.w - tbx.y);
        unsigned long long bk = 0ull;
        for (int i = tid; i < A_N; i += 1024) {
            float4 an = anchors[i];
            float x1 = fmaxf(an.x, tbx.x), y1 = fmaxf(an.y, tbx.y);
            float x2 = fminf(an.z, tbx.z), y2 = fminf(an.w, tbx.w);
            float inter = fmaxf(x2 - x1, 0.f) * fmaxf(y2 - y1, 0.f);
            float a1 = (an.z - an.x) * (an.w - an.y);
            float ue = ((a1 + a2) - inter) + EPSF;
            float iou = inter / ue;
            unsigned long long key = ((unsigned long long)__float_as_uint(iou) << 32)
                                   | (unsigned long long)(~(unsigned int)i);
            if (key > bk) bk = key;
        }
        #pragma unroll
        for (int off = 32; off; off >>= 1) {
            unsigned long long o = __shfl_down(bk, off, 64);
            if (o > bk) bk = o;
        }
        if ((tid & 63) == 0) sw[g] = bk;
        __syncthreads();
        if (tid == 0) {
            unsigned long long m = sw[0];
            #pragma unroll
            for (int i = 1; i < 16; ++i) if (sw[i] > m) m = sw[i];
            winner[tt] = ~(unsigned int)(m & 0xFFFFFFFFull);
        }
        __syncthreads();
    }

    // corrections: first wave, dedupe winners (lowest target owns)
    if (tid < 64) {
        const unsigned int wa = winner[tid];
        bool owner = true;
        for (int k = 0; k < 64; ++k) {
            unsigned int o = __shfl(wa, k, 64);
            if (k < tid && o == wa) owner = false;
        }
        const size_t ba = (size_t)b * A_N + wa;
        const unsigned char c = code[ba];
        float d0 = 0.f, d1 = 0.f, d2 = 0.f, d3 = 0.f;
        if (owner && (c & 128) == 0) {
            const float p = conf[ba];
            float w1 = 1.f - p;
            float f1 = -logf(p + EPSF)       * (w1 * sqrtf(w1)) * 0.5f;
            float f0 = -logf(1.f - p + EPSF) * (p  * sqrtf(p))  * 0.5f;
            d0 = f1 - f0;
            d1 = 1.f;
            const int bt = c & 63;
            const float4 pb = bbox[ba];
            const float4 mb = tboxes[b * T_N + bt];
            float x1 = fmaxf(pb.x, mb.x), y1 = fmaxf(pb.y, mb.y);
            float x2 = fminf(pb.z, mb.z), y2 = fminf(pb.w, mb.w);
            float inter = fmaxf(x2 - x1, 0.f) * fmaxf(y2 - y1, 0.f);
            float pa1 = (pb.z - pb.x) * (pb.w - pb.y);
            float pa2 = (mb.z - mb.x) * (mb.w - mb.y);
            float uni = pa1 + pa2 - inter;
            float iou = inter / (uni + EPSF);
            float ex1 = fminf(pb.x, mb.x), ey1 = fminf(pb.y, mb.y);
            float ex2 = fmaxf(pb.z, mb.z), ey2 = fmaxf(pb.w, mb.w);
            float enc = (ex2 - ex1) * (ey2 - ey1);
            float giou = iou - (enc - uni) / (enc + EPSF);
            float gl = 1.f - giou;
            float l1 = 0.25f * (fabsf(pb.x - mb.x) + fabsf(pb.y - mb.y) +
                                fabsf(pb.z - mb.z) + fabsf(pb.w - mb.w));
            d2 = gl + 0.5f * l1;

            const int lab = tlabels[b * T_N + bt] - 1;
            const float4* cp = cls + ba * 5;
            float s2 = 0.f, xl = 0.f;
            #pragma unroll
            for (int q = 0; q < 5; ++q) {
                float4 v = cp[q];
                float xs[4] = {v.x, v.y, v.z, v.w};
                #pragma unroll
                for (int j = 0; j < 4; ++j) {
                    float x = xs[j];
                    s2 += fmaxf(x, 0.f) + log1pf(expf(-fabsf(x)));
                    if (q * 4 + j == lab) xl = x;
                }
            }
            d3 = (s2 - xl) * (1.f / 20.f);
        }
        #pragma unroll
        for (int off = 32; off; off >>= 1) {
            d0 += __shfl_down(d0, off, 64);
            d1 += __shfl_down(d1, off, 64);
            d2 += __shfl_down(d2, off, 64);
            d3 += __shfl_down(d3, off, 64);
        }
        if (tid == 0) {
            corrections[b * 4 + 0] = d0;
            corrections[b * 4 + 1] = d1;
            corrections[b * 4 + 2] = d2;
            corrections[b * 4 + 3] = d3;
        }
    }
}

// K4: final per-image losses and batch means -> 4 outputs.
__global__ __launch_bounds__(1024) void k4_final(
    const float* __restrict__ partials,
    const float* __restrict__ corrections,
    float* __restrict__ out)
{
    const int tid  = threadIdx.x;
    const int b    = tid >> 6;
    const int lane = tid & 63;
    float s0 = 0.f, s1 = 0.f, s2 = 0.f, s3 = 0.f;
    #pragma unroll
    for (int i = 0; i < 4; ++i) {
        const float* p = partials + (((size_t)b * NB) + (lane + 64 * i)) * 4;
        s0 += p[0]; s1 += p[1]; s2 += p[2]; s3 += p[3];
    }
    #pragma unroll
    for (int off = 32; off; off >>= 1) {
        s0 += __shfl_down(s0, off, 64);
        s1 += __shfl_down(s1, off, 64);
        s2 += __shfl_down(s2, off, 64);
        s3 += __shfl_down(s3, off, 64);
    }
    __shared__ float L[16][3];
    if (lane == 0) {
        s0 += corrections[b * 4 + 0];
        s1 += corrections[b * 4 + 1];
        s2 += corrections[b * 4 + 2];
        s3 += corrections[b * 4 + 3];
        float confL = s0 / (float)A_N;
        float npos  = fmaxf(s1, 1.f);
        L[b][0] = confL;
        L[b][1] = s2 / npos;
        L[b][2] = s3 / npos;
    }
    __syncthreads();
    if (tid == 0) {
        float cm = 0.f, bm = 0.f, lm = 0.f;
        #pragma unroll
        for (int i = 0; i < 16; ++i) { cm += L[i][0]; bm += L[i][1]; lm += L[i][2]; }
        cm *= (1.f / 16.f); bm *= (1.f / 16.f); lm *= (1.f / 16.f);
        out[0] = cm + bm + lm;
        out[1] = cm;
        out[2] = bm;
        out[3] = lm;
    }
}

extern "C" void kernel_launch(void* const* d_in, const int* in_sizes, int n_in,
                              void* d_out, int out_size, void* d_ws, size_t ws_size,
                              hipStream_t stream)
{
    const float4* bbox    = (const float4*)d_in[0];
    const float*  conf    = (const float*) d_in[1];
    const float4* cls     = (const float4*)d_in[2];
    const float4* anchors = (const float4*)d_in[3];
    const float4* tboxes  = (const float4*)d_in[4];
    const int*    tlabels = (const int*)   d_in[5];
    float* out = (float*)d_out;

    char* ws = (char*)d_ws;
    unsigned long long* keys        = (unsigned long long*)ws;                    // 2 MiB
    unsigned char*      code        = (unsigned char*)(ws + (2u << 20));          // 1 MiB
    float*              partials    = (float*)(ws + (3u << 20));                  // 64 KiB
    float*              corrections = (float*)(ws + (3u << 20) + 65536);          // 256 B

    k1_main <<<dim3(NB, B_N), 256, 0, stream>>>(anchors, bbox, conf, cls, tboxes,
                                                tlabels, keys, code, partials);
    k2_all  <<<B_N, 1024, 0, stream>>>(keys, anchors, bbox, conf, cls, tboxes,
                                       tlabels, code, corrections);
    k4_final<<<1, 1024, 0, stream>>>(partials, corrections, out);
}

// Round 4
// 111.435 us; speedup vs baseline: 1.2300x; 1.2300x over previous
//
#include <hip/hip_runtime.h>
#include <stdint.h>
#include <math.h>

#define A_N 65536
#define B_N 16
#define T_N 64
#define NB  (A_N / 256)      // k1 blocks per image = 256
#define EPSF 1e-6f

// ---------------------------------------------------------------------------
// Workspace:
//   keys        : B * NB * 64 * u64  = 2 MiB  (per-block best candidate key per target)
//   code        : B * A * u8         = 1 MiB  (best_target_idx | thr<<7)
//   partials    : B * NB * 4 * f32   = 64 KiB
//   corrections : B * 4 * f32        = 256 B
// ---------------------------------------------------------------------------

__device__ __forceinline__ void emit_cand(
    int s, const float4* tb, const float* ta, float a1, float4 an,
    unsigned int lo, unsigned long long* slot)
{
    const float4 tbx = tb[s];
    float x1 = fmaxf(an.x, tbx.x), y1 = fmaxf(an.y, tbx.y);
    float x2 = fminf(an.z, tbx.z), y2 = fminf(an.w, tbx.w);
    float inter = fmaxf(x2 - x1, 0.f) * fmaxf(y2 - y1, 0.f);
    float ue = ((a1 + ta[s]) - inter) + EPSF;          // np-exact association
    float iou = inter / ue;                            // IEEE-exact
    unsigned long long key = ((unsigned long long)__float_as_uint(iou) << 32)
                           | (unsigned long long)lo;
    atomicMax(&slot[s], key);
}

// K1: branch-free IoU sweep (unroll 4 -> low VGPR, high occupancy)
//     + per-anchor argmax/threshold + candidate bitmask resolved post-loop
//     + loss terms under pos:=thr.
__global__ __launch_bounds__(256) void k1_main(
    const float4* __restrict__ anchors,
    const float4* __restrict__ bbox,
    const float*  __restrict__ conf,
    const float4* __restrict__ cls,       // 20 floats/anchor = 5 x float4
    const float4* __restrict__ tboxes,
    const int*    __restrict__ tlabels,
    unsigned long long* __restrict__ keys,
    unsigned char* __restrict__ code,
    float* __restrict__ partials)
{
    __shared__ float4 tb[T_N];
    __shared__ float  ta[T_N];
    __shared__ int    tl[T_N];
    __shared__ unsigned long long slot[T_N];
    const int b   = blockIdx.y;
    const int tid = threadIdx.x;
    if (tid < T_N) {
        float4 t = tboxes[b * T_N + tid];
        tb[tid] = t;
        ta[tid] = (t.z - t.x) * (t.w - t.y);
        tl[tid] = tlabels[b * T_N + tid];
        slot[tid] = 0ull;
    }
    __syncthreads();

    const int a = blockIdx.x * 256 + tid;
    const float4 an = anchors[a];
    const float a1 = (an.z - an.x) * (an.w - an.y);
    const unsigned int lo = ~(unsigned int)a;   // smaller idx -> larger lo

    // init: first step always wins (inter*1 >= 0 > -ue), then strict-greater
    // keeps the first max (np argmax semantics).
    float b_inter = -1.f, b_ue = 1.f;
    int   b_t = 0;
    unsigned int mlo = 0u, mhi = 0u;

    #pragma unroll 4
    for (int s = 0; s < 64; ++s) {
        const float4 tbx = tb[s];
        const float x1 = fmaxf(an.x, tbx.x), y1 = fmaxf(an.y, tbx.y);
        const float x2 = fminf(an.z, tbx.z), y2 = fminf(an.w, tbx.w);
        const float inter = fmaxf(x2 - x1, 0.f) * fmaxf(y2 - y1, 0.f);
        const float ue = ((a1 + ta[s]) - inter) + EPSF;   // np-exact
        const bool upd = (inter * b_ue > b_inter * ue);
        if (upd) { b_inter = inter; b_ue = ue; b_t = s; }
        // candidate: ratio >= ~0.2499 (margin-safe superset of iou>=0.25)
        const unsigned int c = (fmaf(-0.2499f, ue, inter) >= 0.f) ? 1u : 0u;
        if (s < 32) mlo = mlo + mlo + c;   // bit (31-s)
        else        mhi = mhi + mhi + c;   // bit (63-s)
    }

    // resolve candidates (avg ~0.5/anchor): exact division + LDS atomicMax
    unsigned int w0 = mlo;
    while (w0) {
        int p = __builtin_ctz(w0); w0 &= w0 - 1;
        emit_cand(31 - p, tb, ta, a1, an, lo, slot);
    }
    unsigned int w1 = mhi;
    while (w1) {
        int p = __builtin_ctz(w1); w1 &= w1 - 1;
        emit_cand(63 - p, tb, ta, a1, an, lo, slot);
    }

    const bool thr = (b_inter >= 0.5f * b_ue);   // max_iou >= POS_THR (exact)
    const size_t ba = (size_t)b * A_N + a;
    code[ba] = (unsigned char)(b_t | (thr ? 128 : 0));

    // losses with ct := thr
    const float p  = conf[ba];
    const float w  = thr ? (1.f - p) : p;
    const float fw = w * sqrtf(w);                               // w^1.5
    const float bce = thr ? -logf(p + EPSF) : -logf(1.f - p + EPSF);
    const float cterm = bce * fw * 0.5f;                         // alpha == 0.5

    float bterm = 0.f, clterm = 0.f;
    if (thr) {
        const float4 pb = bbox[ba];
        const float4 mb = tb[b_t];
        float x1 = fmaxf(pb.x, mb.x), y1 = fmaxf(pb.y, mb.y);
        float x2 = fminf(pb.z, mb.z), y2 = fminf(pb.w, mb.w);
        float inter = fmaxf(x2 - x1, 0.f) * fmaxf(y2 - y1, 0.f);
        float pa1 = (pb.z - pb.x) * (pb.w - pb.y);
        float pa2 = (mb.z - mb.x) * (mb.w - mb.y);
        float uni = pa1 + pa2 - inter;
        float iou = inter / (uni + EPSF);
        float ex1 = fminf(pb.x, mb.x), ey1 = fminf(pb.y, mb.y);
        float ex2 = fmaxf(pb.z, mb.z), ey2 = fmaxf(pb.w, mb.w);
        float enc = (ex2 - ex1) * (ey2 - ey1);
        float giou = iou - (enc - uni) / (enc + EPSF);
        float gl = 1.f - giou;
        float l1 = 0.25f * (fabsf(pb.x - mb.x) + fabsf(pb.y - mb.y) +
                            fabsf(pb.z - mb.z) + fabsf(pb.w - mb.w));
        bterm = gl + 0.5f * l1;

        const int lab = tl[b_t] - 1;                // 0..19
        const float4* cp = cls + ba * 5;
        float s2 = 0.f, xl = 0.f;
        #pragma unroll
        for (int q = 0; q < 5; ++q) {
            float4 v = cp[q];
            float xs[4] = {v.x, v.y, v.z, v.w};
            #pragma unroll
            for (int j = 0; j < 4; ++j) {
                float x = xs[j];
                s2 += fmaxf(x, 0.f) + log1pf(expf(-fabsf(x)));
                if (q * 4 + j == lab) xl = x;
            }
        }
        clterm = (s2 - xl) * (1.f / 20.f);
    }

    float r0 = cterm, r1 = thr ? 1.f : 0.f, r2 = bterm, r3 = clterm;
    #pragma unroll
    for (int off = 32; off; off >>= 1) {
        r0 += __shfl_down(r0, off, 64);
        r1 += __shfl_down(r1, off, 64);
        r2 += __shfl_down(r2, off, 64);
        r3 += __shfl_down(r3, off, 64);
    }
    __shared__ float red[4][4];
    const int wv = tid >> 6;
    if ((tid & 63) == 0) { red[wv][0] = r0; red[wv][1] = r1; red[wv][2] = r2; red[wv][3] = r3; }
    __syncthreads();   // also guarantees all slot[] atomics are done
    if (tid < 4) {
        float v = red[0][tid] + red[1][tid] + red[2][tid] + red[3][tid];
        partials[(((size_t)b * NB) + blockIdx.x) * 4 + tid] = v;
    }
    if (tid < T_N)
        keys[(((size_t)b * NB + blockIdx.x) << 6) | tid] = slot[tid];
}

// K2: per image — reduce keys to winners, rare exact fallback for empty
//     targets, then forced-only corrections. One block per image.
__global__ __launch_bounds__(1024) void k2_all(
    const unsigned long long* __restrict__ keys,
    const float4* __restrict__ anchors,
    const float4* __restrict__ bbox,
    const float*  __restrict__ conf,
    const float4* __restrict__ cls,
    const float4* __restrict__ tboxes,
    const int*    __restrict__ tlabels,
    const unsigned char* __restrict__ code,
    float* __restrict__ corrections)
{
    __shared__ unsigned long long sh[16][64];
    __shared__ unsigned long long sw[16];
    __shared__ unsigned int winner[64];
    __shared__ int emptyList[64];
    __shared__ int nEmpty;
    const int b = blockIdx.x, tid = threadIdx.x;
    const int t = tid & 63, g = tid >> 6;
    if (tid == 0) nEmpty = 0;

    unsigned long long K = 0ull;
    #pragma unroll 4
    for (int i = 0; i < 16; ++i) {
        unsigned long long k = keys[(((size_t)b * NB + (g * 16 + i)) << 6) | t];
        if (k > K) K = k;
    }
    sh[g][t] = K;
    __syncthreads();
    if (tid < 64) {
        unsigned long long m = sh[0][tid];
        #pragma unroll
        for (int g2 = 1; g2 < 16; ++g2) if (sh[g2][tid] > m) m = sh[g2][tid];
        if (m != 0ull) winner[tid] = ~(unsigned int)(m & 0xFFFFFFFFull);
        else { int i = atomicAdd(&nEmpty, 1); emptyList[i] = tid; }
    }
    __syncthreads();

    const int ne = nEmpty;            // normally 0
    for (int e = 0; e < ne; ++e) {
        const int tt = emptyList[e];
        const float4 tbx = tboxes[b * T_N + tt];
        const float a2 = (tbx.z - tbx.x) * (tbx.w - tbx.y);
        unsigned long long bk = 0ull;
        for (int i = tid; i < A_N; i += 1024) {
            float4 an = anchors[i];
            float x1 = fmaxf(an.x, tbx.x), y1 = fmaxf(an.y, tbx.y);
            float x2 = fminf(an.z, tbx.z), y2 = fminf(an.w, tbx.w);
            float inter = fmaxf(x2 - x1, 0.f) * fmaxf(y2 - y1, 0.f);
            float a1 = (an.z - an.x) * (an.w - an.y);
            float ue = ((a1 + a2) - inter) + EPSF;
            float iou = inter / ue;
            unsigned long long key = ((unsigned long long)__float_as_uint(iou) << 32)
                                   | (unsigned long long)(~(unsigned int)i);
            if (key > bk) bk = key;
        }
        #pragma unroll
        for (int off = 32; off; off >>= 1) {
            unsigned long long o = __shfl_down(bk, off, 64);
            if (o > bk) bk = o;
        }
        if ((tid & 63) == 0) sw[g] = bk;
        __syncthreads();
        if (tid == 0) {
            unsigned long long m = sw[0];
            #pragma unroll
            for (int i = 1; i < 16; ++i) if (sw[i] > m) m = sw[i];
            winner[tt] = ~(unsigned int)(m & 0xFFFFFFFFull);
        }
        __syncthreads();
    }

    // corrections: first wave, dedupe winners (lowest target owns)
    if (tid < 64) {
        const unsigned int wa = winner[tid];
        bool owner = true;
        for (int k = 0; k < 64; ++k) {
            unsigned int o = __shfl(wa, k, 64);
            if (k < tid && o == wa) owner = false;
        }
        const size_t ba = (size_t)b * A_N + wa;
        const unsigned char c = code[ba];
        float d0 = 0.f, d1 = 0.f, d2 = 0.f, d3 = 0.f;
        if (owner && (c & 128) == 0) {
            const float p = conf[ba];
            float w1 = 1.f - p;
            float f1 = -logf(p + EPSF)       * (w1 * sqrtf(w1)) * 0.5f;
            float f0 = -logf(1.f - p + EPSF) * (p  * sqrtf(p))  * 0.5f;
            d0 = f1 - f0;
            d1 = 1.f;
            const int bt = c & 63;
            const float4 pb = bbox[ba];
            const float4 mb = tboxes[b * T_N + bt];
            float x1 = fmaxf(pb.x, mb.x), y1 = fmaxf(pb.y, mb.y);
            float x2 = fminf(pb.z, mb.z), y2 = fminf(pb.w, mb.w);
            float inter = fmaxf(x2 - x1, 0.f) * fmaxf(y2 - y1, 0.f);
            float pa1 = (pb.z - pb.x) * (pb.w - pb.y);
            float pa2 = (mb.z - mb.x) * (mb.w - mb.y);
            float uni = pa1 + pa2 - inter;
            float iou = inter / (uni + EPSF);
            float ex1 = fminf(pb.x, mb.x), ey1 = fminf(pb.y, mb.y);
            float ex2 = fmaxf(pb.z, mb.z), ey2 = fmaxf(pb.w, mb.w);
            float enc = (ex2 - ex1) * (ey2 - ey1);
            float giou = iou - (enc - uni) / (enc + EPSF);
            float gl = 1.f - giou;
            float l1 = 0.25f * (fabsf(pb.x - mb.x) + fabsf(pb.y - mb.y) +
                                fabsf(pb.z - mb.z) + fabsf(pb.w - mb.w));
            d2 = gl + 0.5f * l1;

            const int lab = tlabels[b * T_N + bt] - 1;
            const float4* cp = cls + ba * 5;
            float s2 = 0.f, xl = 0.f;
            #pragma unroll
            for (int q = 0; q < 5; ++q) {
                float4 v = cp[q];
                float xs[4] = {v.x, v.y, v.z, v.w};
                #pragma unroll
                for (int j = 0; j < 4; ++j) {
                    float x = xs[j];
                    s2 += fmaxf(x, 0.f) + log1pf(expf(-fabsf(x)));
                    if (q * 4 + j == lab) xl = x;
                }
            }
            d3 = (s2 - xl) * (1.f / 20.f);
        }
        #pragma unroll
        for (int off = 32; off; off >>= 1) {
            d0 += __shfl_down(d0, off, 64);
            d1 += __shfl_down(d1, off, 64);
            d2 += __shfl_down(d2, off, 64);
            d3 += __shfl_down(d3, off, 64);
        }
        if (tid == 0) {
            corrections[b * 4 + 0] = d0;
            corrections[b * 4 + 1] = d1;
            corrections[b * 4 + 2] = d2;
            corrections[b * 4 + 3] = d3;
        }
    }
}

// K4: final per-image losses and batch means -> 4 outputs.
__global__ __launch_bounds__(1024) void k4_final(
    const float* __restrict__ partials,
    const float* __restrict__ corrections,
    float* __restrict__ out)
{
    const int tid  = threadIdx.x;
    const int b    = tid >> 6;
    const int lane = tid & 63;
    float s0 = 0.f, s1 = 0.f, s2 = 0.f, s3 = 0.f;
    #pragma unroll
    for (int i = 0; i < 4; ++i) {
        const float* p = partials + (((size_t)b * NB) + (lane + 64 * i)) * 4;
        s0 += p[0]; s1 += p[1]; s2 += p[2]; s3 += p[3];
    }
    #pragma unroll
    for (int off = 32; off; off >>= 1) {
        s0 += __shfl_down(s0, off, 64);
        s1 += __shfl_down(s1, off, 64);
        s2 += __shfl_down(s2, off, 64);
        s3 += __shfl_down(s3, off, 64);
    }
    __shared__ float L[16][3];
    if (lane == 0) {
        s0 += corrections[b * 4 + 0];
        s1 += corrections[b * 4 + 1];
        s2 += corrections[b * 4 + 2];
        s3 += corrections[b * 4 + 3];
        float confL = s0 / (float)A_N;
        float npos  = fmaxf(s1, 1.f);
        L[b][0] = confL;
        L[b][1] = s2 / npos;
        L[b][2] = s3 / npos;
    }
    __syncthreads();
    if (tid == 0) {
        float cm = 0.f, bm = 0.f, lm = 0.f;
        #pragma unroll
        for (int i = 0; i < 16; ++i) { cm += L[i][0]; bm += L[i][1]; lm += L[i][2]; }
        cm *= (1.f / 16.f); bm *= (1.f / 16.f); lm *= (1.f / 16.f);
        out[0] = cm + bm + lm;
        out[1] = cm;
        out[2] = bm;
        out[3] = lm;
    }
}

extern "C" void kernel_launch(void* const* d_in, const int* in_sizes, int n_in,
                              void* d_out, int out_size, void* d_ws, size_t ws_size,
                              hipStream_t stream)
{
    const float4* bbox    = (const float4*)d_in[0];
    const float*  conf    = (const float*) d_in[1];
    const float4* cls     = (const float4*)d_in[2];
    const float4* anchors = (const float4*)d_in[3];
    const float4* tboxes  = (const float4*)d_in[4];
    const int*    tlabels = (const int*)   d_in[5];
    float* out = (float*)d_out;

    char* ws = (char*)d_ws;
    unsigned long long* keys        = (unsigned long long*)ws;                    // 2 MiB
    unsigned char*      code        = (unsigned char*)(ws + (2u << 20));          // 1 MiB
    float*              partials    = (float*)(ws + (3u << 20));                  // 64 KiB
    float*              corrections = (float*)(ws + (3u << 20) + 65536);          // 256 B

    k1_main <<<dim3(NB, B_N), 256, 0, stream>>>(anchors, bbox, conf, cls, tboxes,
                                                tlabels, keys, code, partials);
    k2_all  <<<B_N, 1024, 0, stream>>>(keys, anchors, bbox, conf, cls, tboxes,
                                       tlabels, code, corrections);
    k4_final<<<1, 1024, 0, stream>>>(partials, corrections, out);
}